// Round 5
// baseline (506.123 us; speedup 1.0000x reference)
//
#include <hip/hip_runtime.h>

#define BB 512
#define SS 1024
#define TT 64

__device__ __forceinline__ float wsum64(float v) {
#pragma unroll
  for (int off = 32; off > 0; off >>= 1) v += __shfl_xor(v, off, 64);
  return v;
}

// X-macro list: apply M(i) for i = 0..63
#define E_LIST(M) \
  M(0) M(1) M(2) M(3) M(4) M(5) M(6) M(7) \
  M(8) M(9) M(10) M(11) M(12) M(13) M(14) M(15) \
  M(16) M(17) M(18) M(19) M(20) M(21) M(22) M(23) \
  M(24) M(25) M(26) M(27) M(28) M(29) M(30) M(31) \
  M(32) M(33) M(34) M(35) M(36) M(37) M(38) M(39) \
  M(40) M(41) M(42) M(43) M(44) M(45) M(46) M(47) \
  M(48) M(49) M(50) M(51) M(52) M(53) M(54) M(55) \
  M(56) M(57) M(58) M(59) M(60) M(61) M(62) M(63)

// One quad of the broadcast matvec: read p[4g..4g+3] from LDS (same address in
// all lanes -> broadcast, conflict-free) and FMA against resident E regs.
#define FMAG(g, c0, c1, c2, c3, i0, i1, i2, i3) \
  {                                             \
    float4 q_ = bq[g];                          \
    c0 = fmaf(q_.x, E##i0, c0);                 \
    c1 = fmaf(q_.y, E##i1, c1);                 \
    c2 = fmaf(q_.z, E##i2, c2);                 \
    c3 = fmaf(q_.w, E##i3, c3);                 \
  }

#define FMA_ALL                                   \
  FMAG(0, a0, a1, a2, a3, 0, 1, 2, 3)             \
  FMAG(1, a4, a5, a6, a7, 4, 5, 6, 7)             \
  FMAG(2, a0, a1, a2, a3, 8, 9, 10, 11)           \
  FMAG(3, a4, a5, a6, a7, 12, 13, 14, 15)         \
  FMAG(4, a0, a1, a2, a3, 16, 17, 18, 19)         \
  FMAG(5, a4, a5, a6, a7, 20, 21, 22, 23)         \
  FMAG(6, a0, a1, a2, a3, 24, 25, 26, 27)         \
  FMAG(7, a4, a5, a6, a7, 28, 29, 30, 31)         \
  FMAG(8, a0, a1, a2, a3, 32, 33, 34, 35)         \
  FMAG(9, a4, a5, a6, a7, 36, 37, 38, 39)         \
  FMAG(10, a0, a1, a2, a3, 40, 41, 42, 43)        \
  FMAG(11, a4, a5, a6, a7, 44, 45, 46, 47)        \
  FMAG(12, a0, a1, a2, a3, 48, 49, 50, 51)        \
  FMAG(13, a4, a5, a6, a7, 52, 53, 54, 55)        \
  FMAG(14, a0, a1, a2, a3, 56, 57, 58, 59)        \
  FMAG(15, a4, a5, a6, a7, 60, 61, 62, 63)

// One recurrence step, linear domain, delayed scalar normalization.
// fwd (DIR=0): broadcast p; s_j = sum_i p_i E_ij ; p' = s * (f_j * inv)
// bwd (DIR=1): broadcast t_j = p_j * f_j * inv ; p'_i = sum_j E_ij t_j
// inv = 1/readfirstlane(s) from the PREVIOUS step (off critical path).
#define CRF_STEP(ev, mkv)                                                           \
  do {                                                                              \
    float f_ = __expf((ev) * (mkv));                                                \
    float pv_ = (DIR == 1) ? p * (f_ * inv) : p;                                    \
    bc[lane] = pv_;                                                                 \
    __builtin_amdgcn_wave_barrier();                                                \
    float a0 = 0.f, a1 = 0.f, a2 = 0.f, a3 = 0.f;                                   \
    float a4 = 0.f, a5 = 0.f, a6 = 0.f, a7 = 0.f;                                   \
    FMA_ALL                                                                         \
    float s_ = ((a0 + a4) + (a1 + a5)) + ((a2 + a6) + (a3 + a7));                   \
    p = (DIR == 0) ? s_ * (f_ * inv) : s_;                                          \
    float rn_ = __int_as_float(__builtin_amdgcn_readfirstlane(__float_as_int(s_))); \
    inv = __builtin_amdgcn_rcpf(rn_);                                               \
    float lg_ = __logf(rn_);                                                        \
    Lacc += lg_;                                                                    \
    lastlg = lg_;                                                                   \
  } while (0)

template <int DIR>
__device__ __forceinline__ void part_run(int b, int lane, const float* __restrict__ em,
                                         const float* __restrict__ mask,
                                         const float* __restrict__ trans,
                                         float* __restrict__ outv, float* bc) {
  // Per-lane E fragment as 64 NAMED scalars pinned with opaque asm defs:
  // forbids rematerialization/spill-to-scratch of the table (R4: VGPR=52 showed
  // the allocator was NOT keeping all 64 resident).
  const float* tp = trans + (DIR == 0 ? lane : lane * TT);
#define EINIT(i) float E##i = __expf((DIR == 0) ? tp[(i)*TT] : tp[(i)]);
  E_LIST(EINIT)
#undef EINIT
#define EPIN(i) asm volatile("" : "+v"(E##i));
  E_LIST(EPIN)
#undef EPIN

  const float4* bq = (const float4*)bc;

  const float* emb = em + (size_t)b * SS * TT;
  const float* mkb = mask + (size_t)b * SS;

  constexpr int NST = (DIR == 0) ? (SS / 2 - 1) : (SS / 2);  // 511 fwd, 512 bwd
  constexpr int S0 = (DIR == 0) ? 1 : (SS - 1);
  constexpr int SD = (DIR == 0) ? 1 : -1;
  constexpr int NG8 = NST / 8;    // full groups of 8 steps
  constexpr int TAIL8 = NST & 7;  // 7 fwd, 0 bwd

  float p = (DIR == 0) ? __expf(emb[lane] * mkb[0]) : 1.0f;
  float inv = 1.0f, Lacc = 0.0f, lastlg = 0.0f;

  // 8-deep emission prefetch (coalesced: lane j reads em[b][s][j])
  float ebuf[8];
#pragma unroll
  for (int k = 0; k < 8; ++k) ebuf[k] = emb[(S0 + SD * k) * TT + lane];
  const float* ep = emb + (ptrdiff_t)(S0 + SD * 8) * TT + lane;

  // mask: one coalesced vector load per 64 steps, broadcast via readlane
  float mv = 0.f;
  for (int t8 = 0; t8 < NG8; ++t8) {
    if ((t8 & 7) == 0) mv = mkb[S0 + SD * (t8 * 8 + lane)];
    int base = (t8 & 7) * 8;
#pragma unroll
    for (int k = 0; k < 8; ++k) {
      float e = ebuf[k];
      ebuf[k] = *ep;  // prefetch step t+8; always in-bounds (fwd s<=519, bwd s>=504)
      ep += SD * TT;
      float mk = __int_as_float(
          __builtin_amdgcn_readlane(__float_as_int(mv), base + k));
      CRF_STEP(e, mk);
    }
  }
  if constexpr (TAIL8 > 0) {
#pragma unroll
    for (int k = 0; k < TAIL8; ++k) {
      float e = ebuf[k];
      float mk = __int_as_float(
          __builtin_amdgcn_readlane(__float_as_int(mv), (NG8 & 7) * 8 + k));
      CRF_STEP(e, mk);
    }
  }

  outv[b * TT + lane] = __logf(p) + (Lacc - lastlg);
}

// Fused: blocks [0, 1024) = partition fwd/bwd; blocks [1024, 3072) = gold score
__global__ void __launch_bounds__(64, 1)
    fused_kernel(const float* __restrict__ em, const int* __restrict__ tags,
                 const float* __restrict__ mask, const float* __restrict__ trans,
                 float* __restrict__ alpha, float* __restrict__ beta,
                 float* __restrict__ gpart) {
  __shared__ __align__(16) float bc[TT];
  const int lane = threadIdx.x;
  const int bid = blockIdx.x;
  if (bid < 2 * BB) {
    const int b = bid >> 1;
    if ((bid & 1) == 0)
      part_run<0>(b, lane, em, mask, trans, alpha, bc);
    else
      part_run<1>(b, lane, em, mask, trans, beta, bc);
  } else {
    const int gid = bid - 2 * BB;  // 0..2047
    const int b = gid >> 2, q = gid & 3;
    const int* tg = tags + b * SS;
    const float* mkb = mask + (size_t)b * SS;
    const float* emb = em + (size_t)b * SS * TT;
    float part = 0.f;
#pragma unroll
    for (int i = 0; i < 4; ++i) {
      int s = q * 256 + i * 64 + lane;
      int t1 = tg[s];
      float e = emb[s * TT + t1];
      float contrib = (s == 0) ? e : (trans[t1 * TT + tg[s - 1]] + e);
      part = fmaf(contrib, mkb[s], part);
    }
    part = wsum64(part);
    if (lane == 0) gpart[gid] = part;
  }
}

// Single block, 512 threads: thread b computes Z_b - gold_b, block-reduces, writes mean.
__global__ void combine_kernel(const float* __restrict__ alpha, const float* __restrict__ beta,
                               const float* __restrict__ gpart, float* __restrict__ out) {
  const int b = threadIdx.x;  // 0..511
  const float* av = alpha + b * TT;
  const float* bv = beta + b * TT;
  float m = -3.4e38f, s = 0.f;
#pragma unroll 8
  for (int j = 0; j < TT; ++j) {
    float v = av[j] + bv[j];
    float nm = fmaxf(m, v);
    s = s * __expf(m - nm) + __expf(v - nm);
    m = nm;
  }
  float Z = m + __logf(s);
  float g = gpart[4 * b] + gpart[4 * b + 1] + gpart[4 * b + 2] + gpart[4 * b + 3];
  float val = Z - g;
  val = wsum64(val);
  __shared__ float red[8];
  if ((threadIdx.x & 63) == 0) red[threadIdx.x >> 6] = val;
  __syncthreads();
  if (threadIdx.x == 0) {
    float t = 0.f;
#pragma unroll
    for (int w = 0; w < 8; ++w) t += red[w];
    out[0] = t * (1.0f / (float)BB);
  }
}

extern "C" void kernel_launch(void* const* d_in, const int* in_sizes, int n_in,
                              void* d_out, int out_size, void* d_ws, size_t ws_size,
                              hipStream_t stream) {
  const float* em = (const float*)d_in[0];
  const int* tags = (const int*)d_in[1];
  const float* mask = (const float*)d_in[2];
  const float* trans = (const float*)d_in[3];
  float* out = (float*)d_out;

  float* alpha = (float*)d_ws;      // 512*64
  float* beta = alpha + BB * TT;    // 512*64
  float* gpart = beta + BB * TT;    // 2048

  fused_kernel<<<2 * BB + 4 * BB, TT, 0, stream>>>(em, tags, mask, trans, alpha, beta, gpart);
  combine_kernel<<<1, BB, 0, stream>>>(alpha, beta, gpart, out);
}

// Round 8
// 337.665 us; speedup vs baseline: 1.4989x; 1.4989x over previous
//
#include <hip/hip_runtime.h>

#define BB 512
#define SS 1024
#define TT 64

typedef _Float16 half2v __attribute__((ext_vector_type(2)));

#if __has_builtin(__builtin_amdgcn_fdot2)
#define FDOT2(a, b, c) __builtin_amdgcn_fdot2((a), (b), (c), false)
#else
#define FDOT2(a, b, c) ((c) + (float)(a)[0] * (float)(b)[0] + (float)(a)[1] * (float)(b)[1])
#endif

__device__ __forceinline__ float wsum64(float v) {
#pragma unroll
  for (int off = 32; off > 0; off >>= 1) v += __shfl_xor(v, off, 64);
  return v;
}
__device__ __forceinline__ float wmax64(float v) {
#pragma unroll
  for (int off = 32; off > 0; off >>= 1) v = fmaxf(v, __shfl_xor(v, off, 64));
  return v;
}

// X-macro list: apply M(g) for g = 0..31 (pairs of states)
#define H_LIST(M) \
  M(0) M(1) M(2) M(3) M(4) M(5) M(6) M(7) \
  M(8) M(9) M(10) M(11) M(12) M(13) M(14) M(15) \
  M(16) M(17) M(18) M(19) M(20) M(21) M(22) M(23) \
  M(24) M(25) M(26) M(27) M(28) M(29) M(30) M(31)

// One pair-dot: broadcast packed (p[2g], p[2g+1]) from even lane 2g, dot with
// resident half2 E-pair. readlane -> SGPR (single SGPR operand: legal).
#define DOTG(g, acc)                                                   \
  {                                                                    \
    int sg_ = __builtin_amdgcn_readlane(pk_, 2 * (g));                 \
    acc = FDOT2(__builtin_bit_cast(half2v, sg_), H##g, acc);           \
  }

#define DOT_ALL                                   \
  DOTG(0, a0) DOTG(1, a1) DOTG(2, a2) DOTG(3, a3) \
  DOTG(4, a0) DOTG(5, a1) DOTG(6, a2) DOTG(7, a3) \
  DOTG(8, a0) DOTG(9, a1) DOTG(10, a2) DOTG(11, a3) \
  DOTG(12, a0) DOTG(13, a1) DOTG(14, a2) DOTG(15, a3) \
  DOTG(16, a0) DOTG(17, a1) DOTG(18, a2) DOTG(19, a3) \
  DOTG(20, a0) DOTG(21, a1) DOTG(22, a2) DOTG(23, a3) \
  DOTG(24, a0) DOTG(25, a1) DOTG(26, a2) DOTG(27, a3) \
  DOTG(28, a0) DOTG(29, a1) DOTG(30, a2) DOTG(31, a3)

// One recurrence step, linear domain, delayed scalar normalization.
// fwd (DIR=0): broadcast p (f16 pairs); s_j = sum_i p_i E_ij ; p' = s * (f_j*inv)
// bwd (DIR=1): broadcast t_j = p_j * f_j * inv ; p'_i = sum_j E_ij t_j
// NaN-proofing (R7 post-mortem): f16 RTE casts produce inf above 65504 and
// flush below ~6e-8; either cascades to NaN within 2 steps (inf*0 / 0*inf).
//  - fminf(pv, 3e4) before conversion: a clamped lane dominates the sum, so
//    log distortion is O(1) at worst (threshold is 105.6).
//  - fmaxf(s, 1e-30): p stays > 0, log/inv finite. Small-lane f16 flush is
//    harmless (relative error only).
#define CRF_STEP(ev, mkv)                                                           \
  do {                                                                              \
    float f_ = __expf((ev) * (mkv));                                                \
    float pv_ = (DIR == 1) ? p * (f_ * inv) : p;                                    \
    pv_ = fminf(pv_, 3.0e4f);                                                       \
    int pi_ = __float_as_int(pv_);                                                  \
    int ni_ = __builtin_amdgcn_update_dpp(0, pi_, 0xB1, 0xF, 0xF, true);            \
    half2v pk2_;                                                                    \
    pk2_[0] = (_Float16)pv_;                                                        \
    pk2_[1] = (_Float16)__int_as_float(ni_);                                        \
    int pk_ = __builtin_bit_cast(int, pk2_);                                        \
    float a0 = 0.f, a1 = 0.f, a2 = 0.f, a3 = 0.f;                                   \
    DOT_ALL                                                                         \
    float s_ = fmaxf((a0 + a1) + (a2 + a3), 1e-30f);                                \
    p = (DIR == 0) ? s_ * (f_ * inv) : s_;                                          \
    float rn_ =                                                                     \
        16.0f * __int_as_float(__builtin_amdgcn_readfirstlane(__float_as_int(s_))); \
    inv = __builtin_amdgcn_rcpf(rn_);                                               \
    float lg_ = __logf(rn_);                                                        \
    Lacc += lg_;                                                                    \
    lastlg = lg_;                                                                   \
  } while (0)

template <int DIR>
__device__ __forceinline__ void part_run(int b, int lane, const float* __restrict__ em,
                                         const float* __restrict__ mask,
                                         const float* __restrict__ trans,
                                         float* __restrict__ outv) {
  // Per-lane E fragment as 32 NAMED half2 scalars (32 VGPRs total -> whole
  // working set fits the allocator's ~64-VGPR comfort zone; no spill/remat,
  // no asm pins (R5 lesson: pins force real scratch spills and lose)).
  // fwd lane j: pair g = (E[2g][j], E[2g+1][j]); bwd lane i: (E[i][2g], E[i][2g+1]).
  const float* tp = trans + (DIR == 0 ? lane : lane * TT);
#define HINIT(g)                                                          \
  half2v H##g;                                                            \
  {                                                                       \
    float h0_ = __expf((DIR == 0) ? tp[(2 * (g)) * TT] : tp[2 * (g)]);    \
    float h1_ = __expf((DIR == 0) ? tp[(2 * (g) + 1) * TT] : tp[2 * (g) + 1]); \
    H##g[0] = (_Float16)h0_;                                              \
    H##g[1] = (_Float16)h1_;                                              \
  }
  H_LIST(HINIT)
#undef HINIT

  const float* emb = em + (size_t)b * SS * TT;
  const float* mkb = mask + (size_t)b * SS;

  constexpr int NST = (DIR == 0) ? (SS / 2 - 1) : (SS / 2);  // 511 fwd, 512 bwd
  constexpr int S0 = (DIR == 0) ? 1 : (SS - 1);
  constexpr int SD = (DIR == 0) ? 1 : -1;
  constexpr int NG8 = NST / 8;    // full groups of 8 steps
  constexpr int TAIL8 = NST & 7;  // 7 fwd, 0 bwd

  float p = (DIR == 0) ? __expf(emb[lane] * mkb[0]) : 1.0f;
  float inv = 1.0f, Lacc = 0.0f, lastlg = 0.0f;

  // 8-deep emission prefetch (coalesced: lane j reads em[b][s][j])
  float ebuf[8];
#pragma unroll
  for (int k = 0; k < 8; ++k) ebuf[k] = emb[(S0 + SD * k) * TT + lane];
  const float* ep = emb + (ptrdiff_t)(S0 + SD * 8) * TT + lane;

  // mask: one coalesced vector load per 64 steps, broadcast via readlane
  float mv = 0.f;
  for (int t8 = 0; t8 < NG8; ++t8) {
    if ((t8 & 7) == 0) mv = mkb[S0 + SD * (t8 * 8 + lane)];
    int base = (t8 & 7) * 8;
#pragma unroll
    for (int k = 0; k < 8; ++k) {
      float e = ebuf[k];
      ebuf[k] = *ep;  // prefetch step t+8; always in-bounds (fwd s<=519, bwd s>=504)
      ep += SD * TT;
      float mk = __int_as_float(
          __builtin_amdgcn_readlane(__float_as_int(mv), base + k));
      CRF_STEP(e, mk);
    }
  }
  if constexpr (TAIL8 > 0) {
#pragma unroll
    for (int k = 0; k < TAIL8; ++k) {
      float e = ebuf[k];
      float mk = __int_as_float(
          __builtin_amdgcn_readlane(__float_as_int(mv), (NG8 & 7) * 8 + k));
      CRF_STEP(e, mk);
    }
  }

  outv[b * TT + lane] = __logf(p) + (Lacc - lastlg);
}

// Fused: blocks [0, 1024) = partition fwd/bwd; blocks [1024, 3072) = gold score
__global__ void __launch_bounds__(64, 1)
    fused_kernel(const float* __restrict__ em, const int* __restrict__ tags,
                 const float* __restrict__ mask, const float* __restrict__ trans,
                 float* __restrict__ alpha, float* __restrict__ beta,
                 float* __restrict__ gpart) {
  const int lane = threadIdx.x;
  const int bid = blockIdx.x;
  if (bid < 2 * BB) {
    const int b = bid >> 1;
    if ((bid & 1) == 0)
      part_run<0>(b, lane, em, mask, trans, alpha);
    else
      part_run<1>(b, lane, em, mask, trans, beta);
  } else {
    const int gid = bid - 2 * BB;  // 0..2047
    const int b = gid >> 2, q = gid & 3;
    const int* tg = tags + b * SS;
    const float* mkb = mask + (size_t)b * SS;
    const float* emb = em + (size_t)b * SS * TT;
    float part = 0.f;
#pragma unroll
    for (int i = 0; i < 4; ++i) {
      int s = q * 256 + i * 64 + lane;
      int t1 = tg[s];
      float e = emb[s * TT + t1];
      float contrib = (s == 0) ? e : (trans[t1 * TT + tg[s - 1]] + e);
      part = fmaf(contrib, mkb[s], part);
    }
    part = wsum64(part);
    if (lane == 0) gpart[gid] = part;
  }
}

// 64 blocks x 8 waves; wave w handles batch blockIdx*8+w with coalesced loads.
__global__ void __launch_bounds__(512)
    combine_kernel(const float* __restrict__ alpha, const float* __restrict__ beta,
                   const float* __restrict__ gpart, float* __restrict__ out) {
  const int w = threadIdx.x >> 6;
  const int lane = threadIdx.x & 63;
  const int b = blockIdx.x * 8 + w;
  float v = alpha[b * TT + lane] + beta[b * TT + lane];
  float m = wmax64(v);
  float e = __expf(v - m);
  e = wsum64(e);
  __shared__ float red[8];
  if (lane == 0) {
    float Z = m + __logf(e);
    float g = gpart[4 * b] + gpart[4 * b + 1] + gpart[4 * b + 2] + gpart[4 * b + 3];
    red[w] = Z - g;
  }
  __syncthreads();
  if (threadIdx.x == 0) {
    float t = 0.f;
#pragma unroll
    for (int i = 0; i < 8; ++i) t += red[i];
    atomicAdd(out, t * (1.0f / (float)BB));
  }
}

extern "C" void kernel_launch(void* const* d_in, const int* in_sizes, int n_in,
                              void* d_out, int out_size, void* d_ws, size_t ws_size,
                              hipStream_t stream) {
  const float* em = (const float*)d_in[0];
  const int* tags = (const int*)d_in[1];
  const float* mask = (const float*)d_in[2];
  const float* trans = (const float*)d_in[3];
  float* out = (float*)d_out;

  float* alpha = (float*)d_ws;      // 512*64
  float* beta = alpha + BB * TT;    // 512*64
  float* gpart = beta + BB * TT;    // 2048

  hipMemsetAsync(d_out, 0, sizeof(float), stream);
  fused_kernel<<<2 * BB + 4 * BB, TT, 0, stream>>>(em, tags, mask, trans, alpha, beta, gpart);
  combine_kernel<<<BB / 8, 512, 0, stream>>>(alpha, beta, gpart, out);
}